// Round 19
// baseline (672.108 us; speedup 1.0000x reference)
//
#include <hip/hip_runtime.h>
#include <cstdint>
#include <cstddef>

#define DEV __device__ __forceinline__

typedef unsigned short u16;
typedef _Float16 f16x8 __attribute__((ext_vector_type(8)));
typedef float f32x4 __attribute__((ext_vector_type(4)));

static constexpr int NB  = 16;
static constexpr int T   = 2048;
static constexpr int D   = 512;
static constexpr int DFF = 2048;
static constexpr int NE  = 8;
static constexpr int FEAT = 3 * D;

#define MFMA16 __builtin_amdgcn_mfma_f32_16x16x32_f16

DEV u16 f2h(float f) {
  _Float16 h = (_Float16)f;
  union { _Float16 h; u16 u; } cv; cv.h = h; return cv.u;
}

DEV float gelu_fast(float x) {
  const float t = x * x;
  const float p = x * fmaf(t, -0.07135481627f, -1.59576912161f);  // -2u
  return __fdividef(x, 1.0f + __expf(p));
}

// ---------------- routing path (fp32) ----------------

__global__ void k_part(const float* __restrict__ base, const float* __restrict__ attn,
                       float* __restrict__ part) {
  const int b = blockIdx.x >> 4, ch = blockIdx.x & 15;
  const int d = threadIdx.x;
  const size_t o = ((size_t)b * T + (size_t)ch * 128) * D + d;
  const float* pb = base + o;
  const float* pa = attn + o;
  float sb = 0.f, sa = 0.f;
  for (int r = 0; r < 128; ++r) { sb += pb[(size_t)r * D]; sa += pa[(size_t)r * D]; }
  part[(b * 16 + ch) * D + d] = sb;
  part[NB * 16 * D + (b * 16 + ch) * D + d] = sa;
}

// fused: feat -> router logits (both routers) -> argmax+gate -> btot  (16 blocks x 512)
__global__ void k_router(const float* __restrict__ part,
                         const float* __restrict__ rw0, const float* __restrict__ rb0,
                         const float* __restrict__ rw1, const float* __restrict__ rb1,
                         const float* __restrict__ b2s, const float* __restrict__ b2a,
                         const float* __restrict__ b2e,
                         int* __restrict__ idx, float* __restrict__ gate,
                         float* __restrict__ btot) {
  __shared__ float fsh[FEAT];
  __shared__ float lgsh[2][8];
  __shared__ int   sidx[2];
  __shared__ float sgate[2];
  const int b = blockIdx.x, t = threadIdx.x;

  float sb = 0.f, sa = 0.f;
  for (int ch = 0; ch < 16; ++ch) {
    sb += part[(b * 16 + ch) * D + t];
    sa += part[NB * 16 * D + (b * 16 + ch) * D + t];
  }
  sb *= (1.0f / 2048.0f); sa *= (1.0f / 2048.0f);
  fsh[t] = sb; fsh[D + t] = sa; fsh[2 * D + t] = sa - sb;
  __syncthreads();

  const int wid = t >> 6, lane = t & 63;
  for (int pair = wid; pair < 16; pair += 8) {
    const int r = pair >> 3, e = pair & 7;
    const float* rw = r ? rw1 : rw0;
    float p = 0.f;
    for (int k = lane; k < FEAT; k += 64) p += fsh[k] * rw[e * FEAT + k];
#pragma unroll
    for (int off = 32; off >= 1; off >>= 1) p += __shfl_xor(p, off);
    if (lane == 0) lgsh[r][e] = p + (r ? rb1[e] : rb0[e]);
  }
  __syncthreads();

  if (t < 2) {
    const int r = t;
    float best = -1e30f; int bi = 0;
#pragma unroll
    for (int e = 0; e < 8; ++e)
      if (lgsh[r][e] > best) { best = lgsh[r][e]; bi = e; }
    float s = 0.f;
#pragma unroll
    for (int e = 0; e < 8; ++e) s += expf(lgsh[r][e] - best);
    sidx[r] = bi; sgate[r] = 1.0f / s;
    idx[r * 16 + b] = bi;
    gate[r * 16 + b] = 1.0f / s;
  }
  __syncthreads();

  const int ia = sidx[0], ie = sidx[1];
  const float ga = sgate[0], ge = sgate[1];
  btot[b * D + t] = b2s[t] + ga * b2a[ia * D + t] + ge * b2e[ie * D + t];
}

// ---------------- fp32 -> fp16 casts (merged) ----------------

DEV void cast4(const float* __restrict__ s, u16* __restrict__ d, long i) {
  const float4 v = *(const float4*)(s + i);
  const unsigned int lo = (unsigned int)f2h(v.x) | ((unsigned int)f2h(v.y) << 16);
  const unsigned int hi = (unsigned int)f2h(v.z) | ((unsigned int)f2h(v.w) << 16);
  *(uint2*)(d + i) = make_uint2(lo, hi);
}

__global__ void k_cast3(const float* __restrict__ x, const float* __restrict__ sw1,
                        const float* __restrict__ sw2, u16* __restrict__ xh,
                        u16* __restrict__ w1s, u16* __restrict__ w2s) {
  const long NX = (long)NB * T * D;
  const long NW = (long)DFF * D;
  const long t = ((long)blockIdx.x * 256 + threadIdx.x) * 4;
  if (t < NX)               cast4(x,   xh,  t);
  else if (t < NX + NW)     cast4(sw1, w1s, t - NX);
  else                      cast4(sw2, w2s, t - NX - NW);
}

__global__ void k_castg(const float* __restrict__ aw1, const float* __restrict__ aw2,
                        const float* __restrict__ ew1, const float* __restrict__ ew2,
                        u16* __restrict__ w1a, u16* __restrict__ w2a,
                        u16* __restrict__ w1e, u16* __restrict__ w2e,
                        const int* __restrict__ idx) {
  const int rg = blockIdx.x >> 13;
  const int e  = (blockIdx.x >> 10) & 7;
  const int ro = (rg >= 2) ? 16 : 0;
  bool used = false;
#pragma unroll
  for (int i = 0; i < 16; ++i) used |= (idx[ro + i] == e);
  if (!used) return;
  const long i = (long)e * (DFF * D) + ((long)(blockIdx.x & 1023) * 256 + threadIdx.x) * 4;
  const float* s = (rg == 0) ? aw1 : (rg == 1) ? aw2 : (rg == 2) ? ew1 : ew2;
  u16*         d = (rg == 0) ? w1a : (rg == 1) ? w2a : (rg == 2) ? w1e : w2e;
  cast4(s, d, i);
}

// ---------------- shared core helpers ----------------

DEV void ld_lds16(const void* g, void* l) {
  __builtin_amdgcn_global_load_lds((const __attribute__((address_space(1))) void*)g,
                                   (__attribute__((address_space(3))) void*)l, 16, 0, 0);
}

#define BAR __builtin_amdgcn_s_barrier()
#define LGKM0 do { asm volatile("s_waitcnt lgkmcnt(0)" ::: "memory"); \
                   __builtin_amdgcn_sched_barrier(0); } while (0)
#define VMW8 asm volatile("s_waitcnt vmcnt(8)" ::: "memory")
#define VMW0 asm volatile("s_waitcnt vmcnt(0)" ::: "memory")

// ======== 256x256 core (8 waves), deep pipeline (r18-proven) — used by ffn2 ========
// Full tile t+2 staged during Ph2/Ph3 of tile t into slot sb (B after Ph1-exit
// barrier, A after Ph2-exit); end-of-tile vmcnt(8) keeps a full tile in flight.

#define STG_A(tt, h, sb) do { const long ko_ = (long)(tt) * 64;                          \
    ld_lds16(((h) ? gA10 : gA00) + ko_, (char*)As + (sb) * 32768 + (h) * 16384 + dR0);   \
    ld_lds16(((h) ? gA11 : gA01) + ko_, (char*)As + (sb) * 32768 + (h) * 16384 + dR1); } while (0)
#define STG_B(tt, h, sb) do { const long ko_ = (long)(tt) * 64;                          \
    ld_lds16(((h) ? gB10 : gB00) + ko_, (char*)Bs + (sb) * 32768 + (h) * 16384 + dR0);   \
    ld_lds16(((h) ? gB11 : gB01) + ko_, (char*)Bs + (sb) * 32768 + (h) * 16384 + dR1); } while (0)

#define RD_A(dst, mb, sb) do {                                                           \
    _Pragma("unroll") for (int m_ = 0; m_ < 4; ++m_)                                     \
      _Pragma("unroll") for (int k_ = 0; k_ < 2; ++k_)                                   \
        dst[m_][k_] = *(const f16x8*)((const char*)As + (sb) * 32768 + avb[k_] +         \
                                      ((mb) + m_) * 2048); } while (0)
#define RD_B(dst, nb, sb) do {                                                           \
    _Pragma("unroll") for (int n_ = 0; n_ < 2; ++n_)                                     \
      _Pragma("unroll") for (int k_ = 0; k_ < 2; ++k_)                                   \
        dst[n_][k_] = *(const f16x8*)((const char*)Bs + (sb) * 32768 + bvb[k_] +         \
                                      ((nb) + n_) * 2048); } while (0)

#define QUAD(av, bv, mb, nb) do { __builtin_amdgcn_s_setprio(1);                         \
    _Pragma("unroll") for (int m_ = 0; m_ < 4; ++m_)                                     \
      _Pragma("unroll") for (int n_ = 0; n_ < 2; ++n_) {                                 \
        acc[(mb)+m_][(nb)+n_] = MFMA16(av[m_][0], bv[n_][0], acc[(mb)+m_][(nb)+n_],0,0,0); \
        acc[(mb)+m_][(nb)+n_] = MFMA16(av[m_][1], bv[n_][1], acc[(mb)+m_][(nb)+n_],0,0,0); \
      }                                                                                  \
    __builtin_amdgcn_s_setprio(0); } while (0)

#define TILE(tt, sb, STGN, VMN) do {                                                     \
    RD_A(avLO, 0, sb); RD_B(bvA, 0, sb);                                                 \
    BAR; LGKM0; QUAD(avLO, bvA, 0, 0); BAR;                                              \
    RD_B(bvB, 2, sb);                                                                    \
    BAR; LGKM0; QUAD(avLO, bvB, 0, 2); BAR;                                              \
    RD_A(avHI, 4, sb);                                                                   \
    if (STGN) { STG_B((tt)+2, 0, sb); STG_B((tt)+2, 1, sb); }                            \
    BAR; LGKM0; QUAD(avHI, bvB, 4, 2); BAR;                                              \
    if (STGN) { STG_A((tt)+2, 0, sb); STG_A((tt)+2, 1, sb); }                            \
    BAR; __builtin_amdgcn_sched_barrier(0); QUAD(avHI, bvA, 4, 0);                       \
    if ((VMN) == 8) VMW8; else if ((VMN) == 0) VMW0;                                     \
    BAR;                                                                                 \
  } while (0)

template <int NT>
DEV void gemm_8p(const u16* __restrict__ A, int lda, const u16* __restrict__ B, int ldb,
                 u16* As, u16* Bs, f32x4 (&acc)[8][4]) {
  static_assert(NT >= 8 && (NT % 2) == 0, "NT even, >= 8");
  const int tid = threadIdx.x;
  const int lane = tid & 63, wid = tid >> 6;
  const int wr = wid >> 2, wc = wid & 3;

  const int srow = lane >> 3;
  const int scol = (lane & 7) ^ srow;
  const int rj0 = wid * 16 + srow;
  const int rj1 = rj0 + 8;
  const u16* gA00 = A + (size_t)(  0 + rj0) * lda + scol * 8;
  const u16* gA01 = A + (size_t)(  0 + rj1) * lda + scol * 8;
  const u16* gA10 = A + (size_t)(128 + rj0) * lda + scol * 8;
  const u16* gA11 = A + (size_t)(128 + rj1) * lda + scol * 8;
  const u16* gB00 = B + (size_t)(  0 + rj0) * ldb + scol * 8;
  const u16* gB01 = B + (size_t)(  0 + rj1) * ldb + scol * 8;
  const u16* gB10 = B + (size_t)(128 + rj0) * ldb + scol * 8;
  const u16* gB11 = B + (size_t)(128 + rj1) * ldb + scol * 8;
  const int dR0 = (wid * 16) * 128;
  const int dR1 = dR0 + 1024;

  const int aR = wr * 128 + (lane & 15);
  const int bR = wc * 64 + (lane & 15);
  const int sH = lane >> 4;
  int avb[2], bvb[2];
#pragma unroll
  for (int k_ = 0; k_ < 2; ++k_) {
    const int s_ = (k_ * 4 + sH);
    avb[k_] = aR * 128 + ((s_ ^ (lane & 7)) * 16);
    bvb[k_] = bR * 128 + ((s_ ^ (lane & 7)) * 16);
  }

  f16x8 avLO[4][2], avHI[4][2], bvA[2][2], bvB[2][2];

  STG_A(0, 0, 0); STG_A(0, 1, 0); STG_B(0, 0, 0); STG_B(0, 1, 0);
  STG_A(1, 0, 1); STG_A(1, 1, 1); STG_B(1, 0, 1); STG_B(1, 1, 1);
  VMW8; BAR;

  for (int tp = 0; tp < (NT - 2) / 2; ++tp) {
    TILE(2 * tp,     0, true, 8);
    TILE(2 * tp + 1, 1, true, 8);
  }
  TILE(NT - 2, 0, false, 0);
  TILE(NT - 1, 1, false, -1);
}

// ======== 128x128 core (4 waves, 2 blocks/CU), deep pipeline — used by ffn1 ========
// Same deep choreography as the 256^2 core (r18-validated transformation).

#define STG2_A(tt, h, sb) do { const long ko_ = (long)(tt) * 64;                         \
    ld_lds16(((h) ? qA10 : qA00) + ko_, (char*)As2 + (sb) * 16384 + (h) * 8192 + dQ0);   \
    ld_lds16(((h) ? qA11 : qA01) + ko_, (char*)As2 + (sb) * 16384 + (h) * 8192 + dQ1); } while (0)
#define STG2_B(tt, h, sb) do { const long ko_ = (long)(tt) * 64;                         \
    ld_lds16(((h) ? qB10 : qB00) + ko_, (char*)Bs2 + (sb) * 16384 + (h) * 8192 + dQ0);   \
    ld_lds16(((h) ? qB11 : qB01) + ko_, (char*)Bs2 + (sb) * 16384 + (h) * 8192 + dQ1); } while (0)

#define RD2_A(dst, mb, sb) do {                                                          \
    _Pragma("unroll") for (int m_ = 0; m_ < 2; ++m_)                                     \
      _Pragma("unroll") for (int k_ = 0; k_ < 2; ++k_)                                   \
        dst[m_][k_] = *(const f16x8*)((const char*)As2 + (sb) * 16384 + avb[k_] +        \
                                      ((mb) + m_) * 2048); } while (0)
#define RD2_B(dst, nb, sb) do {                                                          \
    _Pragma("unroll") for (int n_ = 0; n_ < 2; ++n_)                                     \
      _Pragma("unroll") for (int k_ = 0; k_ < 2; ++k_)                                   \
        dst[n_][k_] = *(const f16x8*)((const char*)Bs2 + (sb) * 16384 + bvb[k_] +        \
                                      ((nb) + n_) * 2048); } while (0)

#define QUAD2(av, bv, mb, nb) do { __builtin_amdgcn_s_setprio(1);                        \
    _Pragma("unroll") for (int m_ = 0; m_ < 2; ++m_)                                     \
      _Pragma("unroll") for (int n_ = 0; n_ < 2; ++n_) {                                 \
        acc[(mb)+m_][(nb)+n_] = MFMA16(av[m_][0], bv[n_][0], acc[(mb)+m_][(nb)+n_],0,0,0); \
        acc[(mb)+m_][(nb)+n_] = MFMA16(av[m_][1], bv[n_][1], acc[(mb)+m_][(nb)+n_],0,0,0); \
      }                                                                                  \
    __builtin_amdgcn_s_setprio(0); } while (0)

#define TILE2(tt, sb, STGN, VMN) do {                                                    \
    RD2_A(avLO, 0, sb); RD2_B(bvA, 0, sb);                                               \
    BAR; LGKM0; QUAD2(avLO, bvA, 0, 0); BAR;                                             \
    RD2_B(bvB, 2, sb);                                                                   \
    BAR; LGKM0; QUAD2(avLO, bvB, 0, 2); BAR;                                             \
    RD2_A(avHI, 2, sb);                                                                  \
    if (STGN) { STG2_B((tt)+2, 0, sb); STG2_B((tt)+2, 1, sb); }                          \
    BAR; LGKM0; QUAD2(avHI, bvB, 2, 2); BAR;                                             \
    if (STGN) { STG2_A((tt)+2, 0, sb); STG2_A((tt)+2, 1, sb); }                          \
    BAR; __builtin_amdgcn_sched_barrier(0); QUAD2(avHI, bvA, 2, 0);                      \
    if ((VMN) == 8) VMW8; else if ((VMN) == 0) VMW0;                                     \
    BAR;                                                                                 \
  } while (0)

// ---------------- GEMM1: h = gate * gelu(x @ W1^T + b1) — deep 128^2 core --------
// 128^2 tile, 256 threads, 64 KB LDS -> 2 blocks/CU. Grid 4096 (16b x 16mt x 16nt).
template <int BANK>
__global__ __launch_bounds__(256) void k_ffn1(
    const u16* __restrict__ xh, const u16* __restrict__ w1, const float* __restrict__ b1,
    const int* __restrict__ idx, const float* __restrict__ gate, u16* __restrict__ h) {
  __shared__ alignas(16) u16 As2[2 * 8192];
  __shared__ alignas(16) u16 Bs2[2 * 8192];
  int wg = blockIdx.x;
  const int q = (int)gridDim.x >> 3;             // 4096/8 = 512
  wg = (wg & 7) * q + (wg >> 3);                 // XCD-contiguous tiles
  const int b  = wg >> 8;
  const int mt = (wg >> 4) & 15;
  const int nt = wg & 15;

  const int e   = (BANK == 0) ? 0 : idx[(BANK - 1) * 16 + b];
  const float g = (BANK == 0) ? 1.0f : gate[(BANK - 1) * 16 + b];
  const u16* A = xh + ((size_t)b * T + (size_t)mt * 128) * D;
  const u16* B = w1 + (size_t)e * DFF * D + (size_t)nt * 128 * D;
  const float* bb = b1 + (size_t)e * DFF;

  const int tid = threadIdx.x;
  const int lane = tid & 63, wid = tid >> 6;     // 4 waves
  const int wr = wid >> 1, wc = wid & 1;         // 2 (M) x 2 (N)

  const int srow = lane >> 3;
  const int scol = (lane & 7) ^ srow;
  const int r0 = wid * 8 + srow;
  const u16* qA00 = A + (size_t)(  0 + r0) * D + scol * 8;
  const u16* qA01 = A + (size_t)( 32 + r0) * D + scol * 8;
  const u16* qA10 = A + (size_t)( 64 + r0) * D + scol * 8;
  const u16* qA11 = A + (size_t)( 96 + r0) * D + scol * 8;
  const u16* qB00 = B + (size_t)(  0 + r0) * D + scol * 8;
  const u16* qB01 = B + (size_t)( 32 + r0) * D + scol * 8;
  const u16* qB10 = B + (size_t)( 64 + r0) * D + scol * 8;
  const u16* qB11 = B + (size_t)( 96 + r0) * D + scol * 8;
  const int dQ0 = wid * 1024;
  const int dQ1 = dQ0 + 4096;

  const int aR = wr * 64 + (lane & 15);
  const int bR = wc * 64 + (lane & 15);
  const int sH = lane >> 4;
  int avb[2], bvb[2];
#pragma unroll
  for (int k_ = 0; k_ < 2; ++k_) {
    const int s_ = (k_ * 4 + sH);
    avb[k_] = aR * 128 + ((s_ ^ (aR & 7)) * 16);
    bvb[k_] = bR * 128 + ((s_ ^ (bR & 7)) * 16);
  }

  f32x4 acc[4][4];
#pragma unroll
  for (int m = 0; m < 4; ++m)
#pragma unroll
    for (int n = 0; n < 4; ++n)
#pragma unroll
      for (int r = 0; r < 4; ++r) acc[m][n][r] = 0.f;

  f16x8 avLO[2][2], avHI[2][2], bvA[2][2], bvB[2][2];

  // prologue: tiles 0 and 1 fully staged (16 loads); VMW8 -> tile 0 landed
  STG2_A(0, 0, 0); STG2_A(0, 1, 0); STG2_B(0, 0, 0); STG2_B(0, 1, 0);
  STG2_A(1, 0, 1); STG2_A(1, 1, 1); STG2_B(1, 0, 1); STG2_B(1, 1, 1);
  VMW8; BAR;

  TILE2(0, 0, true, 8);
  TILE2(1, 1, true, 8);
  TILE2(2, 0, true, 8);
  TILE2(3, 1, true, 8);
  TILE2(4, 0, true, 8);
  TILE2(5, 1, true, 8);
  TILE2(6, 0, false, 0);
  TILE2(7, 1, false, -1);

  // epilogue: gelu -> per-wave LDS repack (16x72 u16) -> coalesced dwordx4 stores
  const int rr = (lane >> 4) << 2, cc = lane & 15;
  const int mrow = mt * 128 + wr * 64;
  const int ncol = nt * 128 + wc * 64;
  u16* hb = h + (size_t)b * T * DFF;
  u16* wsl = (u16*)As2 + wid * 1152;
  const int rdrow = lane >> 2;
  const int rdcb  = lane & 3;
  float bias[4];
#pragma unroll
  for (int n = 0; n < 4; ++n) bias[n] = bb[ncol + n * 16 + cc];
#pragma unroll
  for (int m = 0; m < 4; ++m) {
#pragma unroll
    for (int n = 0; n < 4; ++n) {
      const f32x4 a = acc[m][n];
#pragma unroll
      for (int r = 0; r < 4; ++r)
        wsl[(rr + r) * 72 + n * 16 + cc] = f2h(gelu_fast(a[r] + bias[n]) * g);
    }
    asm volatile("s_waitcnt lgkmcnt(0)" ::: "memory");
    __builtin_amdgcn_sched_barrier(0);
    const uint4 v0 = *(const uint4*)(wsl + rdrow * 72 + rdcb * 16);
    const uint4 v1 = *(const uint4*)(wsl + rdrow * 72 + rdcb * 16 + 8);
    u16* dst = hb + (size_t)(mrow + m * 16 + rdrow) * DFF + ncol + rdcb * 16;
    *(uint4*)dst = v0;
    *(uint4*)(dst + 8) = v1;
    asm volatile("s_waitcnt lgkmcnt(0)" ::: "memory");
    __builtin_amdgcn_sched_barrier(0);
  }
}

// ---------------- GEMM2: out (+)= h @ W2^T (+ btot on bank 0) — deep 256^2 -------
template <int BANK>
__global__ __launch_bounds__(512) void k_ffn2(
    const u16* __restrict__ h, const u16* __restrict__ w2, const float* __restrict__ btot,
    const int* __restrict__ idx, float* __restrict__ out) {
  __shared__ alignas(16) u16 As[2 * 16384];
  __shared__ alignas(16) u16 Bs[2 * 16384];
  int wg = blockIdx.x;
  const int q = (int)gridDim.x >> 3;             // 256/8 = 32
  wg = (wg & 7) * q + (wg >> 3);
  const int b  = wg >> 4;
  const int mt = (wg >> 1) & 7;
  const int nt = wg & 1;

  const int e = (BANK == 0) ? 0 : idx[(BANK - 1) * 16 + b];
  const u16* Ab = h + ((size_t)b * T + (size_t)mt * 256) * DFF;
  const u16* Bb = w2 + (size_t)e * D * DFF + (size_t)nt * 256 * DFF;

  f32x4 acc[8][4];
#pragma unroll
  for (int m = 0; m < 8; ++m)
#pragma unroll
    for (int n = 0; n < 4; ++n)
#pragma unroll
      for (int r = 0; r < 4; ++r) acc[m][n][r] = 0.f;

  gemm_8p<32>(Ab, DFF, Bb, DFF, As, Bs, acc);

  const int lane = threadIdx.x & 63, wid = threadIdx.x >> 6;
  const int wr = wid >> 2, wc = wid & 3;
  const int rr = (lane >> 4) << 2, cc = lane & 15;
  const int mrow = mt * 256 + wr * 128;
  const int ncol = nt * 256 + wc * 64;
  float* ob = out + (size_t)b * T * D;
  float* wsl = (float*)(void*)As + wid * (16 * 68);
  float btv[4];
#pragma unroll
  for (int n = 0; n < 4; ++n)
    btv[n] = (BANK == 0) ? btot[b * D + ncol + n * 16 + cc] : 0.f;
#pragma unroll
  for (int m = 0; m < 8; ++m) {
#pragma unroll
    for (int n = 0; n < 4; ++n) {
      const f32x4 a = acc[m][n];
#pragma unroll
      for (int r = 0; r < 4; ++r)
        wsl[(rr + r) * 68 + n * 16 + cc] = a[r] + btv[n];
    }
    asm volatile("s_waitcnt lgkmcnt(0)" ::: "memory");
    __builtin_amdgcn_sched_barrier(0);
#pragma unroll
    for (int j = 0; j < 4; ++j) {
      const int row = j * 4 + (lane >> 4);
      const int colb = lane & 15;
      f32x4 v = *(const f32x4*)(wsl + row * 68 + colb * 4);
      float* dst = ob + (size_t)(mrow + m * 16 + row) * D + ncol + colb * 4;
      if (BANK != 0) { const f32x4 o = *(const f32x4*)dst; v += o; }
      *(f32x4*)dst = v;
    }
    asm volatile("s_waitcnt lgkmcnt(0)" ::: "memory");
    __builtin_amdgcn_sched_barrier(0);
  }
}

// ---------------- launch ----------------

extern "C" void kernel_launch(void* const* d_in, const int* in_sizes, int n_in,
                              void* d_out, int out_size, void* d_ws, size_t ws_size,
                              hipStream_t stream) {
  (void)in_sizes; (void)n_in; (void)out_size; (void)ws_size;
  const float* x    = (const float*)d_in[0];
  const float* base = (const float*)d_in[1];
  const float* attn = (const float*)d_in[2];
  const float* sw1  = (const float*)d_in[3];
  const float* sb1  = (const float*)d_in[4];
  const float* sw2  = (const float*)d_in[5];
  const float* sb2  = (const float*)d_in[6];
  const float* arw  = (const float*)d_in[7];
  const float* arb  = (const float*)d_in[8];
  const float* erw  = (const float*)d_in[9];
  const float* erb  = (const float*)d_in[10];
  const float* aw1  = (const float*)d_in[11];
  const float* ab1  = (const float*)d_in[12];
  const float* aw2  = (const float*)d_in[13];
  const float* ab2  = (const float*)d_in[14];
  const float* ew1  = (const float*)d_in[15];
  const float* eb1  = (const float*)d_in[16];
  const float* ew2  = (const float*)d_in[17];
  const float* eb2  = (const float*)d_in[18];
  float* out = (float*)d_out;

  // proven-footprint layout (~242 MB)
  char* w = (char*)d_ws;
  u16* xh   = (u16*)w;  w += (size_t)NB * T * D * 2;
  u16* hbuf = (u16*)w;  w += (size_t)NB * T * DFF * 2;
  u16* w1s  = (u16*)w;  w += (size_t)DFF * D * 2;
  u16* w2s  = (u16*)w;  w += (size_t)D * DFF * 2;
  u16* w1a  = (u16*)w;  w += (size_t)NE * DFF * D * 2;
  u16* w2a  = (u16*)w;  w += (size_t)NE * D * DFF * 2;
  u16* w1e  = (u16*)w;  w += (size_t)NE * DFF * D * 2;
  u16* w2e  = (u16*)w;  w += (size_t)NE * D * DFF * 2;
  float* part = (float*)w; w += (size_t)2 * NB * 16 * D * 4;
  int*   idx  = (int*)w;   w += 32 * 4;
  float* gate = (float*)w; w += 32 * 4;
  float* btot = (float*)w; w += (size_t)NB * D * 4;

  // routing path (2 dispatches)
  k_part<<<dim3(256), dim3(512), 0, stream>>>(base, attn, part);
  k_router<<<dim3(16), dim3(512), 0, stream>>>(part, arw, arb, erw, erb,
                                               sb2, ab2, eb2, idx, gate, btot);

  // fp32 -> fp16 casts (2 dispatches; expert weights gated via idx scan)
  k_cast3<<<dim3(18432), 256, 0, stream>>>(x, sw1, sw2, xh, w1s, w2s);
  k_castg<<<dim3(32768), 256, 0, stream>>>(aw1, aw2, ew1, ew2, w1a, w2a, w1e, w2e, idx);

  // three bank passes (stream-serialized: ffn2<k> reads hbuf written by ffn1<k>)
  const dim3 g1(4096), g2(256), blk1(256), blk2(512);
  k_ffn1<0><<<g1, blk1, 0, stream>>>(xh, w1s, sb1, idx, gate, hbuf);
  k_ffn2<0><<<g2, blk2, 0, stream>>>(hbuf, w2s, btot, idx, out);
  k_ffn1<1><<<g1, blk1, 0, stream>>>(xh, w1a, ab1, idx, gate, hbuf);
  k_ffn2<1><<<g2, blk2, 0, stream>>>(hbuf, w2a, btot, idx, out);
  k_ffn1<2><<<g1, blk1, 0, stream>>>(xh, w1e, eb1, idx, gate, hbuf);
  k_ffn2<2><<<g2, blk2, 0, stream>>>(hbuf, w2e, btot, idx, out);
}

// Round 20
// 669.793 us; speedup vs baseline: 1.0035x; 1.0035x over previous
//
#include <hip/hip_runtime.h>
#include <cstdint>
#include <cstddef>

#define DEV __device__ __forceinline__

typedef unsigned short u16;
typedef _Float16 f16x8 __attribute__((ext_vector_type(8)));
typedef float f32x4 __attribute__((ext_vector_type(4)));

static constexpr int NB  = 16;
static constexpr int T   = 2048;
static constexpr int D   = 512;
static constexpr int DFF = 2048;
static constexpr int NE  = 8;
static constexpr int FEAT = 3 * D;

#define MFMA16 __builtin_amdgcn_mfma_f32_16x16x32_f16

DEV u16 f2h(float f) {
  _Float16 h = (_Float16)f;
  union { _Float16 h; u16 u; } cv; cv.h = h; return cv.u;
}

DEV float gelu_fast(float x) {
  const float t = x * x;
  const float p = x * fmaf(t, -0.07135481627f, -1.59576912161f);  // -2u
  return __fdividef(x, 1.0f + __expf(p));
}

// ---------------- routing path (fp32) ----------------

__global__ void k_part(const float* __restrict__ base, const float* __restrict__ attn,
                       float* __restrict__ part) {
  const int b = blockIdx.x >> 4, ch = blockIdx.x & 15;
  const int d = threadIdx.x;
  const size_t o = ((size_t)b * T + (size_t)ch * 128) * D + d;
  const float* pb = base + o;
  const float* pa = attn + o;
  float sb = 0.f, sa = 0.f;
  for (int r = 0; r < 128; ++r) { sb += pb[(size_t)r * D]; sa += pa[(size_t)r * D]; }
  part[(b * 16 + ch) * D + d] = sb;
  part[NB * 16 * D + (b * 16 + ch) * D + d] = sa;
}

// fused: feat -> router logits (both routers) -> argmax+gate -> btot  (16 blocks x 512)
__global__ void k_router(const float* __restrict__ part,
                         const float* __restrict__ rw0, const float* __restrict__ rb0,
                         const float* __restrict__ rw1, const float* __restrict__ rb1,
                         const float* __restrict__ b2s, const float* __restrict__ b2a,
                         const float* __restrict__ b2e,
                         int* __restrict__ idx, float* __restrict__ gate,
                         float* __restrict__ btot) {
  __shared__ float fsh[FEAT];
  __shared__ float lgsh[2][8];
  __shared__ int   sidx[2];
  __shared__ float sgate[2];
  const int b = blockIdx.x, t = threadIdx.x;

  float sb = 0.f, sa = 0.f;
  for (int ch = 0; ch < 16; ++ch) {
    sb += part[(b * 16 + ch) * D + t];
    sa += part[NB * 16 * D + (b * 16 + ch) * D + t];
  }
  sb *= (1.0f / 2048.0f); sa *= (1.0f / 2048.0f);
  fsh[t] = sb; fsh[D + t] = sa; fsh[2 * D + t] = sa - sb;
  __syncthreads();

  const int wid = t >> 6, lane = t & 63;
  for (int pair = wid; pair < 16; pair += 8) {
    const int r = pair >> 3, e = pair & 7;
    const float* rw = r ? rw1 : rw0;
    float p = 0.f;
    for (int k = lane; k < FEAT; k += 64) p += fsh[k] * rw[e * FEAT + k];
#pragma unroll
    for (int off = 32; off >= 1; off >>= 1) p += __shfl_xor(p, off);
    if (lane == 0) lgsh[r][e] = p + (r ? rb1[e] : rb0[e]);
  }
  __syncthreads();

  if (t < 2) {
    const int r = t;
    float best = -1e30f; int bi = 0;
#pragma unroll
    for (int e = 0; e < 8; ++e)
      if (lgsh[r][e] > best) { best = lgsh[r][e]; bi = e; }
    float s = 0.f;
#pragma unroll
    for (int e = 0; e < 8; ++e) s += expf(lgsh[r][e] - best);
    sidx[r] = bi; sgate[r] = 1.0f / s;
    idx[r * 16 + b] = bi;
    gate[r * 16 + b] = 1.0f / s;
  }
  __syncthreads();

  const int ia = sidx[0], ie = sidx[1];
  const float ga = sgate[0], ge = sgate[1];
  btot[b * D + t] = b2s[t] + ga * b2a[ia * D + t] + ge * b2e[ie * D + t];
}

// ---------------- fp32 -> fp16 casts (merged) ----------------

DEV void cast4(const float* __restrict__ s, u16* __restrict__ d, long i) {
  const float4 v = *(const float4*)(s + i);
  const unsigned int lo = (unsigned int)f2h(v.x) | ((unsigned int)f2h(v.y) << 16);
  const unsigned int hi = (unsigned int)f2h(v.z) | ((unsigned int)f2h(v.w) << 16);
  *(uint2*)(d + i) = make_uint2(lo, hi);
}

__global__ void k_cast3(const float* __restrict__ x, const float* __restrict__ sw1,
                        const float* __restrict__ sw2, u16* __restrict__ xh,
                        u16* __restrict__ w1s, u16* __restrict__ w2s) {
  const long NX = (long)NB * T * D;
  const long NW = (long)DFF * D;
  const long t = ((long)blockIdx.x * 256 + threadIdx.x) * 4;
  if (t < NX)               cast4(x,   xh,  t);
  else if (t < NX + NW)     cast4(sw1, w1s, t - NX);
  else                      cast4(sw2, w2s, t - NX - NW);
}

__global__ void k_castg(const float* __restrict__ aw1, const float* __restrict__ aw2,
                        const float* __restrict__ ew1, const float* __restrict__ ew2,
                        u16* __restrict__ w1a, u16* __restrict__ w2a,
                        u16* __restrict__ w1e, u16* __restrict__ w2e,
                        const int* __restrict__ idx) {
  const int rg = blockIdx.x >> 13;
  const int e  = (blockIdx.x >> 10) & 7;
  const int ro = (rg >= 2) ? 16 : 0;
  bool used = false;
#pragma unroll
  for (int i = 0; i < 16; ++i) used |= (idx[ro + i] == e);
  if (!used) return;
  const long i = (long)e * (DFF * D) + ((long)(blockIdx.x & 1023) * 256 + threadIdx.x) * 4;
  const float* s = (rg == 0) ? aw1 : (rg == 1) ? aw2 : (rg == 2) ? ew1 : ew2;
  u16*         d = (rg == 0) ? w1a : (rg == 1) ? w2a : (rg == 2) ? w1e : w2e;
  cast4(s, d, i);
}

// ---------------- shared core helpers ----------------

DEV void ld_lds16(const void* g, void* l) {
  __builtin_amdgcn_global_load_lds((const __attribute__((address_space(1))) void*)g,
                                   (__attribute__((address_space(3))) void*)l, 16, 0, 0);
}

#define BAR __builtin_amdgcn_s_barrier()
#define LGKM0 do { asm volatile("s_waitcnt lgkmcnt(0)" ::: "memory"); \
                   __builtin_amdgcn_sched_barrier(0); } while (0)
#define VMW8 asm volatile("s_waitcnt vmcnt(8)" ::: "memory")
#define VMW0 asm volatile("s_waitcnt vmcnt(0)" ::: "memory")

// ======== 256x256 core (8 waves), deep pipeline (r18-proven) ========
// Full tile t+2 staged during Ph2/Ph3 of tile t into slot sb (B after Ph1-exit
// barrier, A after Ph2-exit); end-of-tile vmcnt(8) keeps a full tile in flight.
// Per-wave VMW8 at end of t-1 drains each wave's stages of tile t before the
// trailing barrier -> tile-t ds_reads (issued post-barrier) are safe cross-wave.

#define STG_A(tt, h, sb) do { const long ko_ = (long)(tt) * 64;                          \
    ld_lds16(((h) ? gA10 : gA00) + ko_, (char*)As + (sb) * 32768 + (h) * 16384 + dR0);   \
    ld_lds16(((h) ? gA11 : gA01) + ko_, (char*)As + (sb) * 32768 + (h) * 16384 + dR1); } while (0)
#define STG_B(tt, h, sb) do { const long ko_ = (long)(tt) * 64;                          \
    ld_lds16(((h) ? gB10 : gB00) + ko_, (char*)Bs + (sb) * 32768 + (h) * 16384 + dR0);   \
    ld_lds16(((h) ? gB11 : gB01) + ko_, (char*)Bs + (sb) * 32768 + (h) * 16384 + dR1); } while (0)

#define RD_A(dst, mb, sb) do {                                                           \
    _Pragma("unroll") for (int m_ = 0; m_ < 4; ++m_)                                     \
      _Pragma("unroll") for (int k_ = 0; k_ < 2; ++k_)                                   \
        dst[m_][k_] = *(const f16x8*)((const char*)As + (sb) * 32768 + avb[k_] +         \
                                      ((mb) + m_) * 2048); } while (0)
#define RD_B(dst, nb, sb) do {                                                           \
    _Pragma("unroll") for (int n_ = 0; n_ < 2; ++n_)                                     \
      _Pragma("unroll") for (int k_ = 0; k_ < 2; ++k_)                                   \
        dst[n_][k_] = *(const f16x8*)((const char*)Bs + (sb) * 32768 + bvb[k_] +         \
                                      ((nb) + n_) * 2048); } while (0)

#define QUAD(av, bv, mb, nb) do { __builtin_amdgcn_s_setprio(1);                         \
    _Pragma("unroll") for (int m_ = 0; m_ < 4; ++m_)                                     \
      _Pragma("unroll") for (int n_ = 0; n_ < 2; ++n_) {                                 \
        acc[(mb)+m_][(nb)+n_] = MFMA16(av[m_][0], bv[n_][0], acc[(mb)+m_][(nb)+n_],0,0,0); \
        acc[(mb)+m_][(nb)+n_] = MFMA16(av[m_][1], bv[n_][1], acc[(mb)+m_][(nb)+n_],0,0,0); \
      }                                                                                  \
    __builtin_amdgcn_s_setprio(0); } while (0)

#define TILE(tt, sb, STGN, VMN) do {                                                     \
    RD_A(avLO, 0, sb); RD_B(bvA, 0, sb);                                                 \
    BAR; LGKM0; QUAD(avLO, bvA, 0, 0); BAR;                                              \
    RD_B(bvB, 2, sb);                                                                    \
    BAR; LGKM0; QUAD(avLO, bvB, 0, 2); BAR;                                              \
    RD_A(avHI, 4, sb);                                                                   \
    if (STGN) { STG_B((tt)+2, 0, sb); STG_B((tt)+2, 1, sb); }                            \
    BAR; LGKM0; QUAD(avHI, bvB, 4, 2); BAR;                                              \
    if (STGN) { STG_A((tt)+2, 0, sb); STG_A((tt)+2, 1, sb); }                            \
    BAR; __builtin_amdgcn_sched_barrier(0); QUAD(avHI, bvA, 4, 0);                       \
    if ((VMN) == 8) VMW8; else if ((VMN) == 0) VMW0;                                     \
    BAR;                                                                                 \
  } while (0)

template <int NT>
DEV void gemm_8p(const u16* __restrict__ A, int lda, const u16* __restrict__ B, int ldb,
                 u16* As, u16* Bs, f32x4 (&acc)[8][4]) {
  static_assert(NT >= 8 && (NT % 2) == 0, "NT even, >= 8");
  const int tid = threadIdx.x;
  const int lane = tid & 63, wid = tid >> 6;
  const int wr = wid >> 2, wc = wid & 3;

  const int srow = lane >> 3;
  const int scol = (lane & 7) ^ srow;
  const int rj0 = wid * 16 + srow;
  const int rj1 = rj0 + 8;
  const u16* gA00 = A + (size_t)(  0 + rj0) * lda + scol * 8;
  const u16* gA01 = A + (size_t)(  0 + rj1) * lda + scol * 8;
  const u16* gA10 = A + (size_t)(128 + rj0) * lda + scol * 8;
  const u16* gA11 = A + (size_t)(128 + rj1) * lda + scol * 8;
  const u16* gB00 = B + (size_t)(  0 + rj0) * ldb + scol * 8;
  const u16* gB01 = B + (size_t)(  0 + rj1) * ldb + scol * 8;
  const u16* gB10 = B + (size_t)(128 + rj0) * ldb + scol * 8;
  const u16* gB11 = B + (size_t)(128 + rj1) * ldb + scol * 8;
  const int dR0 = (wid * 16) * 128;
  const int dR1 = dR0 + 1024;

  const int aR = wr * 128 + (lane & 15);
  const int bR = wc * 64 + (lane & 15);
  const int sH = lane >> 4;
  int avb[2], bvb[2];
#pragma unroll
  for (int k_ = 0; k_ < 2; ++k_) {
    const int s_ = (k_ * 4 + sH);
    avb[k_] = aR * 128 + ((s_ ^ (lane & 7)) * 16);
    bvb[k_] = bR * 128 + ((s_ ^ (lane & 7)) * 16);
  }

  f16x8 avLO[4][2], avHI[4][2], bvA[2][2], bvB[2][2];

  // prologue: tiles 0 and 1 fully staged (16 loads); VMW8 -> tile 0 landed
  STG_A(0, 0, 0); STG_A(0, 1, 0); STG_B(0, 0, 0); STG_B(0, 1, 0);
  STG_A(1, 0, 1); STG_A(1, 1, 1); STG_B(1, 0, 1); STG_B(1, 1, 1);
  VMW8; BAR;

  for (int tp = 0; tp < (NT - 2) / 2; ++tp) {
    TILE(2 * tp,     0, true, 8);
    TILE(2 * tp + 1, 1, true, 8);
  }
  TILE(NT - 2, 0, false, 0);
  TILE(NT - 1, 1, false, -1);
}

// ---------------- GEMM1: h = gate * gelu(x @ W1^T + b1) ----------------
// 256^2 tile, 512 threads (8 waves), grid 1024 (16b x 8mt x 8nt).
template <int BANK>
__global__ __launch_bounds__(512) void k_ffn1(
    const u16* __restrict__ xh, const u16* __restrict__ w1, const float* __restrict__ b1,
    const int* __restrict__ idx, const float* __restrict__ gate, u16* __restrict__ h) {
  __shared__ alignas(16) u16 As[2 * 16384];
  __shared__ alignas(16) u16 Bs[2 * 16384];
  int wg = blockIdx.x;
  const int q = (int)gridDim.x >> 3;             // 1024/8 = 128
  wg = (wg & 7) * q + (wg >> 3);                 // XCD-contiguous tiles
  const int b  = wg >> 6;
  const int mt = (wg >> 3) & 7;
  const int nt = wg & 7;

  const int e   = (BANK == 0) ? 0 : idx[(BANK - 1) * 16 + b];
  const float g = (BANK == 0) ? 1.0f : gate[(BANK - 1) * 16 + b];
  const u16* Ab = xh + ((size_t)b * T + (size_t)mt * 256) * D;
  const u16* Bb = w1 + (size_t)e * DFF * D + (size_t)nt * 256 * D;
  const float* bb = b1 + (size_t)e * DFF;

  f32x4 acc[8][4];
#pragma unroll
  for (int m = 0; m < 8; ++m)
#pragma unroll
    for (int n = 0; n < 4; ++n)
#pragma unroll
      for (int r = 0; r < 4; ++r) acc[m][n][r] = 0.f;

  gemm_8p<8>(Ab, D, Bb, D, As, Bs, acc);

  // epilogue: gelu -> LDS repack (stride-72 u16, per-wave slice in As, terminal reuse)
  const int lane = threadIdx.x & 63, wid = threadIdx.x >> 6;
  const int wr = wid >> 2, wc = wid & 3;
  const int rr = (lane >> 4) << 2, cc = lane & 15;
  const int mrow = mt * 256 + wr * 128;
  const int ncol = nt * 256 + wc * 64;
  u16* hb = h + (size_t)b * T * DFF;
  u16* wsl = (u16*)As + wid * (16 * 72);
  const int rdrow = lane >> 2;
  const int rdcb  = (lane & 3) * 2;
  float bias[4];
#pragma unroll
  for (int n = 0; n < 4; ++n) bias[n] = bb[ncol + n * 16 + cc];
#pragma unroll
  for (int m = 0; m < 8; ++m) {
#pragma unroll
    for (int n = 0; n < 4; ++n) {
      const f32x4 a = acc[m][n];
#pragma unroll
      for (int r = 0; r < 4; ++r)
        wsl[(rr + r) * 72 + n * 16 + cc] = f2h(gelu_fast(a[r] + bias[n]) * g);
    }
    asm volatile("s_waitcnt lgkmcnt(0)" ::: "memory");
    __builtin_amdgcn_sched_barrier(0);
    const uint4 v0 = *(const uint4*)(wsl + rdrow * 72 + rdcb * 8);
    const uint4 v1 = *(const uint4*)(wsl + rdrow * 72 + rdcb * 8 + 8);
    u16* dst = hb + (size_t)(mrow + m * 16 + rdrow) * DFF + ncol + rdcb * 8;
    *(uint4*)dst = v0;
    *(uint4*)(dst + 8) = v1;
    asm volatile("s_waitcnt lgkmcnt(0)" ::: "memory");
    __builtin_amdgcn_sched_barrier(0);
  }
}

// ---------------- GEMM2: out (+)= h @ W2^T (+ btot on bank 0) ----------------
template <int BANK>
__global__ __launch_bounds__(512) void k_ffn2(
    const u16* __restrict__ h, const u16* __restrict__ w2, const float* __restrict__ btot,
    const int* __restrict__ idx, float* __restrict__ out) {
  __shared__ alignas(16) u16 As[2 * 16384];
  __shared__ alignas(16) u16 Bs[2 * 16384];
  int wg = blockIdx.x;
  const int q = (int)gridDim.x >> 3;             // 256/8 = 32
  wg = (wg & 7) * q + (wg >> 3);
  const int b  = wg >> 4;
  const int mt = (wg >> 1) & 7;
  const int nt = wg & 1;

  const int e = (BANK == 0) ? 0 : idx[(BANK - 1) * 16 + b];
  const u16* Ab = h + ((size_t)b * T + (size_t)mt * 256) * DFF;
  const u16* Bb = w2 + (size_t)e * D * DFF + (size_t)nt * 256 * DFF;

  f32x4 acc[8][4];
#pragma unroll
  for (int m = 0; m < 8; ++m)
#pragma unroll
    for (int n = 0; n < 4; ++n)
#pragma unroll
      for (int r = 0; r < 4; ++r) acc[m][n][r] = 0.f;

  gemm_8p<32>(Ab, DFF, Bb, DFF, As, Bs, acc);

  const int lane = threadIdx.x & 63, wid = threadIdx.x >> 6;
  const int wr = wid >> 2, wc = wid & 3;
  const int rr = (lane >> 4) << 2, cc = lane & 15;
  const int mrow = mt * 256 + wr * 128;
  const int ncol = nt * 256 + wc * 64;
  float* ob = out + (size_t)b * T * D;
  float* wsl = (float*)(void*)As + wid * (16 * 68);
  float btv[4];
#pragma unroll
  for (int n = 0; n < 4; ++n)
    btv[n] = (BANK == 0) ? btot[b * D + ncol + n * 16 + cc] : 0.f;
#pragma unroll
  for (int m = 0; m < 8; ++m) {
#pragma unroll
    for (int n = 0; n < 4; ++n) {
      const f32x4 a = acc[m][n];
#pragma unroll
      for (int r = 0; r < 4; ++r)
        wsl[(rr + r) * 68 + n * 16 + cc] = a[r] + btv[n];
    }
    asm volatile("s_waitcnt lgkmcnt(0)" ::: "memory");
    __builtin_amdgcn_sched_barrier(0);
#pragma unroll
    for (int j = 0; j < 4; ++j) {
      const int row = j * 4 + (lane >> 4);
      const int colb = lane & 15;
      f32x4 v = *(const f32x4*)(wsl + row * 68 + colb * 4);
      float* dst = ob + (size_t)(mrow + m * 16 + row) * D + ncol + colb * 4;
      if (BANK != 0) { const f32x4 o = *(const f32x4*)dst; v += o; }
      *(f32x4*)dst = v;
    }
    asm volatile("s_waitcnt lgkmcnt(0)" ::: "memory");
    __builtin_amdgcn_sched_barrier(0);
  }
}

// ---------------- launch ----------------

extern "C" void kernel_launch(void* const* d_in, const int* in_sizes, int n_in,
                              void* d_out, int out_size, void* d_ws, size_t ws_size,
                              hipStream_t stream) {
  (void)in_sizes; (void)n_in; (void)out_size; (void)ws_size;
  const float* x    = (const float*)d_in[0];
  const float* base = (const float*)d_in[1];
  const float* attn = (const float*)d_in[2];
  const float* sw1  = (const float*)d_in[3];
  const float* sb1  = (const float*)d_in[4];
  const float* sw2  = (const float*)d_in[5];
  const float* sb2  = (const float*)d_in[6];
  const float* arw  = (const float*)d_in[7];
  const float* arb  = (const float*)d_in[8];
  const float* erw  = (const float*)d_in[9];
  const float* erb  = (const float*)d_in[10];
  const float* aw1  = (const float*)d_in[11];
  const float* ab1  = (const float*)d_in[12];
  const float* aw2  = (const float*)d_in[13];
  const float* ab2  = (const float*)d_in[14];
  const float* ew1  = (const float*)d_in[15];
  const float* eb1  = (const float*)d_in[16];
  const float* ew2  = (const float*)d_in[17];
  const float* eb2  = (const float*)d_in[18];
  float* out = (float*)d_out;

  // proven-footprint layout (~242 MB)
  char* w = (char*)d_ws;
  u16* xh   = (u16*)w;  w += (size_t)NB * T * D * 2;
  u16* hbuf = (u16*)w;  w += (size_t)NB * T * DFF * 2;
  u16* w1s  = (u16*)w;  w += (size_t)DFF * D * 2;
  u16* w2s  = (u16*)w;  w += (size_t)D * DFF * 2;
  u16* w1a  = (u16*)w;  w += (size_t)NE * DFF * D * 2;
  u16* w2a  = (u16*)w;  w += (size_t)NE * D * DFF * 2;
  u16* w1e  = (u16*)w;  w += (size_t)NE * DFF * D * 2;
  u16* w2e  = (u16*)w;  w += (size_t)NE * D * DFF * 2;
  float* part = (float*)w; w += (size_t)2 * NB * 16 * D * 4;
  int*   idx  = (int*)w;   w += 32 * 4;
  float* gate = (float*)w; w += 32 * 4;
  float* btot = (float*)w; w += (size_t)NB * D * 4;

  // routing path (2 dispatches)
  k_part<<<dim3(256), dim3(512), 0, stream>>>(base, attn, part);
  k_router<<<dim3(16), dim3(512), 0, stream>>>(part, arw, arb, erw, erb,
                                               sb2, ab2, eb2, idx, gate, btot);

  // fp32 -> fp16 casts (2 dispatches; expert weights gated via idx scan)
  k_cast3<<<dim3(18432), 256, 0, stream>>>(x, sw1, sw2, xh, w1s, w2s);
  k_castg<<<dim3(32768), 256, 0, stream>>>(aw1, aw2, ew1, ew2, w1a, w2a, w1e, w2e, idx);

  // three bank passes (stream-serialized: ffn2<k> reads hbuf written by ffn1<k>)
  const dim3 g1(1024), g2(256), blk(512);
  k_ffn1<0><<<g1, blk, 0, stream>>>(xh, w1s, sb1, idx, gate, hbuf);
  k_ffn2<0><<<g2, blk, 0, stream>>>(hbuf, w2s, btot, idx, out);
  k_ffn1<1><<<g1, blk, 0, stream>>>(xh, w1a, ab1, idx, gate, hbuf);
  k_ffn2<1><<<g2, blk, 0, stream>>>(hbuf, w2a, btot, idx, out);
  k_ffn1<2><<<g1, blk, 0, stream>>>(xh, w1e, eb1, idx, gate, hbuf);
  k_ffn2<2><<<g2, blk, 0, stream>>>(hbuf, w2e, btot, idx, out);
}